// Round 1
// baseline (451.047 us; speedup 1.0000x reference)
//
#include <hip/hip_runtime.h>
#include <stdint.h>

// Fused attention: S=(x1@x2^T)*0.2; P=softmax(S); P=mask?P/0.9:0; O=P@x3
// B=16, SQ=SK=2048, D=DV=128. fp32 in/out, int32 mask, bf16 MFMA compute.
//
// R4 changes vs R3 (170us/dispatch):
//  1. XCD-chunked block swizzle: hardware assigns wg -> XCD by (blockIdx%8).
//     Remap so XCD x owns batches {2x,2x+1} and the two co-resident blocks
//     of a CU share a batch. All blocks scan K/V tiles in the same order ->
//     lockstep L2 reuse. Kills the ~8x K/V HBM over-fetch (268MB -> ~34MB).
//     Bijective: 512 blocks % 8 == 0.
//  2. v_cvt_pk_bf16_f32 (1 instr per f32-pair, RNE, no builtin -> inline asm)
//     replaces the manual bit-twiddle RNE pack (~8 VALU/pair) in K/V/Q/Ps
//     staging: ~280 -> ~70 staging VALU ops per thread per tile.
//  Carried from R3: V-transpose k-rotation swizzle (write banks 2-way),
//  static-max softmax p=exp(0.2*s-12) (no per-tile reductions; denominator
//  reduced once in epilogue), register double-buffer of K/V/mask prefetch.

#define B_   16
#define SQ_  2048
#define SK_  2048
#define D_   128
#define DV_  128

#define BQ   64
#define BK   64
#define NT   (SK_ / BK)   // 32 tiles
#define LDQ  136          // bf16 elems: 128 + 8 pad
#define LDK  136
#define LDVT 72           // V^T rows: 64 + 8 pad
#define LDP  72

typedef short  s16x8 __attribute__((ext_vector_type(8)));   // MFMA A/B frag
typedef float  f32x4 __attribute__((ext_vector_type(4)));   // MFMA C/D frag
typedef unsigned short u16;
typedef unsigned int   u32;

// f32 pair -> packed bf16x2, RNE, single instruction (no builtin on gfx950).
__device__ __forceinline__ u32 pk2(float a, float b) {
    u32 r;
    asm("v_cvt_pk_bf16_f32 %0, %1, %2" : "=v"(r) : "v"(a), "v"(b));
    return r;
}
__device__ __forceinline__ u16 f2bf(float f) {   // single f32 -> bf16 (1 instr)
    return (u16)pk2(f, 0.0f);
}

__global__ __launch_bounds__(256, 2)
void fattn_kernel(const float* __restrict__ Qg, const float* __restrict__ Kg,
                  const float* __restrict__ Vg, const int* __restrict__ Mg,
                  float* __restrict__ Og)
{
    __shared__ u16 Qs[BQ * LDQ];        // 17408 B
    __shared__ u16 Ks[BK * LDK];        // 17408 B
    __shared__ u16 Vt[DV_ * LDVT];      // 18432 B (V^T, k-rotated rows)
    __shared__ u16 Ps[4 * 16 * LDP];    //  9216 B
    // 62464 B -> 2 blocks/CU; grid 512 = 2 blocks/CU

    const int tid  = threadIdx.x;
    const int wave = tid >> 6;
    const int lane = tid & 63;
    const int n16  = lane & 15;
    const int quad = lane >> 4;

    // ---- XCD-chunked swizzle (bijective, 512 % 8 == 0) ----
    // raw%8 = XCD. XCD x gets batches {2x, 2x+1}; co-resident CU pair
    // (raw, raw+256) -> same batch (j and j+32 have equal parity).
    const int raw = blockIdx.x;
    const int xcd = raw & 7;
    const int j   = raw >> 3;            // 0..63
    const int b   = xcd * 2 + (j & 1);   // batch
    const int q0  = (j >> 1) << 6;       // q-tile origin

    // staging decomposition: e = c*2048 + tid*8 -> row = c*16 + (tid>>4), col = (tid&15)*8
    const int srow = tid >> 4;          // 0..15
    const int scol = (tid & 15) * 8;    // 0..120
    const int vrot = (tid & 7) * 8;     // V k-rotation for this thread's dv block

    // ---- stage Q tile (fp32 -> bf16) ----
    {
        const float* src = Qg + ((size_t)b * SQ_ + q0) * D_;
        #pragma unroll
        for (int c = 0; c < 4; ++c) {
            int row = c * 16 + srow;
            float4 v0 = *(const float4*)(&src[row * D_ + scol]);
            float4 v1 = *(const float4*)(&src[row * D_ + scol + 4]);
            uint4 pk = { pk2(v0.x, v0.y), pk2(v0.z, v0.w),
                         pk2(v1.x, v1.y), pk2(v1.z, v1.w) };
            *(uint4*)(&Qs[row * LDQ + scol]) = pk;
        }
    }
    __syncthreads();

    s16x8 aQ[4];
    {
        const int qr = wave * 16 + n16;
        #pragma unroll
        for (int kb = 0; kb < 4; ++kb)
            aQ[kb] = *(const s16x8*)(&Qs[qr * LDQ + kb * 32 + quad * 8]);
    }

    f32x4 o[8];
    #pragma unroll
    for (int i = 0; i < 8; ++i) o[i] = (f32x4){0.f, 0.f, 0.f, 0.f};
    float l_part[4] = {0.f, 0.f, 0.f, 0.f};   // per-lane partial exp-sums

    const size_t mask_qbase = ((size_t)b * SQ_ + q0 + wave * 16 + quad * 4) * (size_t)SK_;
    const float* baseK = Kg + ((size_t)b * SK_) * D_;
    const float* baseV = Vg + ((size_t)b * SK_) * DV_;

    // ---- prefetch tile 0: K/V into regs, mask into regs ----
    float4 kf[8], vf[8];
    #pragma unroll
    for (int c = 0; c < 4; ++c) {
        int row = c * 16 + srow;
        kf[2*c]   = *(const float4*)(&baseK[row * D_ + scol]);
        kf[2*c+1] = *(const float4*)(&baseK[row * D_ + scol + 4]);
        vf[2*c]   = *(const float4*)(&baseV[row * DV_ + scol]);
        vf[2*c+1] = *(const float4*)(&baseV[row * DV_ + scol + 4]);
    }
    int mkc[4][4], mkn[4][4];
    #pragma unroll
    for (int t = 0; t < 4; ++t)
        #pragma unroll
        for (int r = 0; r < 4; ++r)
            mkc[t][r] = Mg[mask_qbase + (size_t)r * SK_ + (t * 16 + n16)];

    for (int it = 0; it < NT; ++it) {
        __syncthreads();   // all waves done reading Ks/Vt from previous tile

        // ---- write staged regs -> LDS (fp32 -> bf16 via v_cvt_pk) ----
        #pragma unroll
        for (int c = 0; c < 4; ++c) {
            int row = c * 16 + srow;
            uint4 pk = { pk2(kf[2*c].x, kf[2*c].y),     pk2(kf[2*c].z, kf[2*c].w),
                         pk2(kf[2*c+1].x, kf[2*c+1].y), pk2(kf[2*c+1].z, kf[2*c+1].w) };
            *(uint4*)(&Ks[row * LDK + scol]) = pk;
        }
        #pragma unroll
        for (int c = 0; c < 4; ++c) {
            int k    = c * 16 + srow;      // V source row = k index
            int rcol = (k + vrot) & 63;    // rotated column (same for dv0..dv0+7)
            int dv0  = scol;
            u32 r0 = pk2(vf[2*c].x,   vf[2*c].y);
            u32 r1 = pk2(vf[2*c].z,   vf[2*c].w);
            u32 r2 = pk2(vf[2*c+1].x, vf[2*c+1].y);
            u32 r3 = pk2(vf[2*c+1].z, vf[2*c+1].w);
            Vt[(dv0 + 0) * LDVT + rcol] = (u16)r0;
            Vt[(dv0 + 1) * LDVT + rcol] = (u16)(r0 >> 16);
            Vt[(dv0 + 2) * LDVT + rcol] = (u16)r1;
            Vt[(dv0 + 3) * LDVT + rcol] = (u16)(r1 >> 16);
            Vt[(dv0 + 4) * LDVT + rcol] = (u16)r2;
            Vt[(dv0 + 5) * LDVT + rcol] = (u16)(r2 >> 16);
            Vt[(dv0 + 6) * LDVT + rcol] = (u16)r3;
            Vt[(dv0 + 7) * LDVT + rcol] = (u16)(r3 >> 16);
        }

        // ---- issue prefetch for tile it+1 (latency spans the compute phase) ----
        if (it + 1 < NT) {
            const int k0n = (it + 1) * BK;
            #pragma unroll
            for (int c = 0; c < 4; ++c) {
                int row = k0n + c * 16 + srow;
                kf[2*c]   = *(const float4*)(&baseK[row * D_ + scol]);
                kf[2*c+1] = *(const float4*)(&baseK[row * D_ + scol + 4]);
                vf[2*c]   = *(const float4*)(&baseV[row * DV_ + scol]);
                vf[2*c+1] = *(const float4*)(&baseV[row * DV_ + scol + 4]);
            }
            #pragma unroll
            for (int t = 0; t < 4; ++t)
                #pragma unroll
                for (int r = 0; r < 4; ++r)
                    mkn[t][r] = Mg[mask_qbase + (size_t)r * SK_ + (k0n + t * 16 + n16)];
        }

        __syncthreads();   // staging visible

        // ---- S = Q K^T (16 q-rows x 64 k-cols per wave) ----
        f32x4 s[4];
        #pragma unroll
        for (int t = 0; t < 4; ++t) s[t] = (f32x4){0.f, 0.f, 0.f, 0.f};
        #pragma unroll
        for (int kb = 0; kb < 4; ++kb) {
            #pragma unroll
            for (int t = 0; t < 4; ++t) {
                s16x8 bK = *(const s16x8*)(&Ks[(t * 16 + n16) * LDK + kb * 32 + quad * 8]);
                s[t] = __builtin_amdgcn_mfma_f32_16x16x32_bf16(aQ[kb], bK, s[t], 0, 0, 0);
            }
        }

        // ---- static-max softmax: p = exp(0.2*s - 12); shift cancels in 1/sum ----
        #pragma unroll
        for (int t = 0; t < 4; ++t)
            #pragma unroll
            for (int r = 0; r < 4; ++r) {
                float p = __expf(fmaf(s[t][r], 0.2f, -12.0f));
                l_part[r] += p;                               // UNmasked denominator
                float pv = mkc[t][r] ? p : 0.f;               // dropout
                Ps[(wave * 16 + quad * 4 + r) * LDP + t * 16 + n16] = f2bf(pv);
            }

        // ---- O += P V (wave-local Ps; Vt reads use rotation) ----
        #pragma unroll
        for (int kk = 0; kk < 2; ++kk) {
            s16x8 aP = *(const s16x8*)(&Ps[(wave * 16 + n16) * LDP + kk * 32 + quad * 8]);
            #pragma unroll
            for (int nt = 0; nt < 8; ++nt) {
                int dv   = nt * 16 + n16;
                int rcol = (kk * 32 + quad * 8 + 8 * ((dv >> 3) & 7)) & 63;
                s16x8 bV = *(const s16x8*)(&Vt[dv * LDVT + rcol]);
                o[nt] = __builtin_amdgcn_mfma_f32_16x16x32_bf16(aP, bV, o[nt], 0, 0, 0);
            }
        }

        // rotate mask regs
        #pragma unroll
        for (int t = 0; t < 4; ++t)
            #pragma unroll
            for (int r = 0; r < 4; ++r) mkc[t][r] = mkn[t][r];
    }

    // ---- epilogue: reduce l across the 16 lanes of each quad-row, scale, store ----
    const float keep_scale = 1.0f / 0.9f;
    #pragma unroll
    for (int r = 0; r < 4; ++r) {
        float l = l_part[r];
        #pragma unroll
        for (int off = 1; off < 16; off <<= 1)
            l += __shfl_xor(l, off);
        float inv_l = keep_scale / l;
        size_t obase = ((size_t)b * SQ_ + q0 + wave * 16 + quad * 4 + r) * DV_;
        #pragma unroll
        for (int nt = 0; nt < 8; ++nt)
            Og[obase + nt * 16 + n16] = o[nt][r] * inv_l;
    }
}

extern "C" void kernel_launch(void* const* d_in, const int* in_sizes, int n_in,
                              void* d_out, int out_size, void* d_ws, size_t ws_size,
                              hipStream_t stream) {
    const float* Qg = (const float*)d_in[0];
    const float* Kg = (const float*)d_in[1];
    const float* Vg = (const float*)d_in[2];
    const int*   Mg = (const int*)d_in[3];
    float* Og = (float*)d_out;
    dim3 grid(B_ * (SQ_ / BQ));   // 512 blocks
    fattn_kernel<<<grid, 256, 0, stream>>>(Qg, Kg, Vg, Mg, Og);
}